// Round 4
// baseline (508.028 us; speedup 1.0000x reference)
//
#include <hip/hip_runtime.h>

#define HB 32
#define HT 256
#define HC 2048
#define HH 16
#define HD 128
#define HM (HB * HT)  // 8192

typedef __bf16 bf16x8 __attribute__((ext_vector_type(8)));
typedef float f32x4 __attribute__((ext_vector_type(4)));

__device__ __forceinline__ unsigned short f2bf(float f) {
  unsigned u = __float_as_uint(f);
  u += 0x7FFFu + ((u >> 16) & 1u);  // round-to-nearest-even
  return (unsigned short)(u >> 16);
}

// ---------------- fused fp32 -> bf16 convert (x + 4 weights) ----------------
__global__ __launch_bounds__(256) void cvt_all(
    const float* __restrict__ x, const float* __restrict__ wq, const float* __restrict__ wk,
    const float* __restrict__ wv, const float* __restrict__ wo,
    unsigned short* __restrict__ xb, unsigned short* __restrict__ wqb,
    unsigned short* __restrict__ wkb, unsigned short* __restrict__ wvb,
    unsigned short* __restrict__ wob) {
  size_t i = (size_t)blockIdx.x * 256 + threadIdx.x;
  const float* src;
  unsigned short* dst;
  size_t off;
  if (i < 4194304) {
    src = x; dst = xb; off = i;
  } else {
    size_t j = i - 4194304;
    int w = (int)(j >> 20);
    off = j & 1048575;
    src = (w == 0) ? wq : (w == 1) ? wk : (w == 2) ? wv : wo;
    dst = (w == 0) ? wqb : (w == 1) ? wkb : (w == 2) ? wvb : wob;
  }
  float4 v = ((const float4*)src)[off];
  ushort4 o;
  o.x = f2bf(v.x); o.y = f2bf(v.y); o.z = f2bf(v.z); o.w = f2bf(v.w);
  ((ushort4*)dst)[off] = o;
}

// ---------------- GEMM core: 128x256 block tile, BK=64, 16x16x32 MFMA ----------------
// Round-3 verified config (SQ_LDS_BANK_CONFLICT = 0, 204 us for 3 GEMMs): 4 waves,
// 48 KiB, stage-all -> barrier -> compute, 2 blocks/CU inter-block overlap. Tiles as
// two [rows][32] k-half planes (64B pitch); fragment reads 16 consecutive rows at
// chunk = quad ^ ((l16>>1)&3) -> 2-way max (free, m136). DO NOT restructure: 8-phase
// at this occupancy regressed twice (rounds 1-2); m131/m99 say source pipelining on
// this structure is neutral.
__device__ __forceinline__ void gl_lds16(const unsigned short* g, unsigned short* l) {
  __builtin_amdgcn_global_load_lds((const __attribute__((address_space(1))) void*)g,
                                   (__attribute__((address_space(3))) void*)l, 16, 0, 0);
}

// Per wave: 64x128 output = acc[4 m-frags][8 n-frags], 16x16x32 MFMA.
// C-layout (m89-verified): row = quad*4 + reg, col = l16.
__device__ __forceinline__ void gemm_core_wide(const unsigned short* __restrict__ Ab,
                                               const unsigned short* __restrict__ Wb,
                                               unsigned short* lsA, unsigned short* lsB,
                                               f32x4 acc[4][8], int tid) {
  const int lane = tid & 63, wave = tid >> 6;
  const int l16 = lane & 15, quad = lane >> 4;
  const int wr = wave >> 1, wc = wave & 1;
  // swizzle is row-independent at 16-aligned fragment rows: bits 1-2 of row == bits 1-2 of l16
  const int ch = (quad ^ ((l16 >> 1) & 3)) * 8;

  for (int kt = 0; kt < HC / 64; ++kt) {
    __syncthreads();
    // stage A: [2 kh][128 rows][32] = 1024 x 16B chunks; vrow = kh*128 + row
#pragma unroll
    for (int i = 0; i < 4; i++) {
      int c = i * 256 + tid;
      int vrow = c >> 2, slot = c & 3;
      int gc = slot ^ ((vrow >> 1) & 3);
      int row = vrow & 127, kh = vrow >> 7;
      gl_lds16(Ab + (size_t)row * HC + kt * 64 + kh * 32 + gc * 8, lsA + c * 8);
    }
    // stage B: [2 kh][256 rows][32] = 2048 chunks
#pragma unroll
    for (int i = 0; i < 8; i++) {
      int c = i * 256 + tid;
      int vrow = c >> 2, slot = c & 3;
      int gc = slot ^ ((vrow >> 1) & 3);
      int row = vrow & 255, kh = vrow >> 8;
      gl_lds16(Wb + (size_t)row * HC + kt * 64 + kh * 32 + gc * 8, lsB + c * 8);
    }
    __syncthreads();
#pragma unroll
    for (int kh = 0; kh < 2; ++kh) {
      bf16x8 af[4], bfr[8];
#pragma unroll
      for (int mi = 0; mi < 4; mi++) {
        int r = wr * 64 + mi * 16 + l16;
        af[mi] = *(const bf16x8*)(lsA + (kh * 128 + r) * 32 + ch);
      }
#pragma unroll
      for (int nj = 0; nj < 8; nj++) {
        int r = wc * 128 + nj * 16 + l16;
        bfr[nj] = *(const bf16x8*)(lsB + (kh * 256 + r) * 32 + ch);
      }
#pragma unroll
      for (int mi = 0; mi < 4; mi++)
#pragma unroll
        for (int nj = 0; nj < 8; nj++)
          acc[mi][nj] = __builtin_amdgcn_mfma_f32_16x16x32_bf16(af[mi], bfr[nj], acc[mi][nj], 0, 0, 0);
    }
  }
}

// Output projection GEMM: fp32 out [M, 2048]; grid (64, 8)
__global__ __launch_bounds__(256, 2) void gemm_out(const unsigned short* __restrict__ A,
                                                   const unsigned short* __restrict__ W,
                                                   float* __restrict__ outp) {
  __shared__ __align__(16) unsigned short lsA[2 * 128 * 32];
  __shared__ __align__(16) unsigned short lsB[2 * 256 * 32];
  const int tid = threadIdx.x;
  const int lane = tid & 63, wave = tid >> 6;
  const int l16 = lane & 15, quad = lane >> 4;
  const int wr = wave >> 1, wc = wave & 1;
  const int bm = blockIdx.x, bn = blockIdx.y;

  f32x4 acc[4][8];
#pragma unroll
  for (int i = 0; i < 4; i++)
#pragma unroll
    for (int j = 0; j < 8; j++) acc[i][j] = f32x4{0.f, 0.f, 0.f, 0.f};

  gemm_core_wide(A + (size_t)bm * 128 * HC, W + (size_t)bn * 256 * HC, lsA, lsB, acc, tid);

#pragma unroll
  for (int mi = 0; mi < 4; mi++)
#pragma unroll
    for (int nj = 0; nj < 8; nj++) {
      const int n = bn * 256 + wc * 128 + nj * 16 + l16;
#pragma unroll
      for (int rr = 0; rr < 4; rr++) {
        const int m = bm * 128 + wr * 64 + mi * 16 + quad * 4 + rr;
        outp[(size_t)m * HC + n] = acc[mi][nj][rr];
      }
    }
}

// Q or K projection GEMM with fused RoPE: grid (64, 8). Launched twice (wq->Qo, wk->Ko).
// Wave's 128 cols = one head: h = bn*2 + wc. RoPE pair: acc[mi][nj] (d) with
// acc[mi][nj+4] (d+64), d = nj*16 + l16, nj in {0..3}.
__global__ __launch_bounds__(256, 2) void gemm_qk(const unsigned short* __restrict__ A,
                                                  const unsigned short* __restrict__ W,
                                                  unsigned short* __restrict__ outp) {
  __shared__ __align__(16) unsigned short lsA[2 * 128 * 32];
  __shared__ __align__(16) unsigned short lsB[2 * 256 * 32];
  const int tid = threadIdx.x;
  const int lane = tid & 63, wave = tid >> 6;
  const int l16 = lane & 15, quad = lane >> 4;
  const int wr = wave >> 1, wc = wave & 1;
  const int bm = blockIdx.x, bn = blockIdx.y;

  f32x4 acc[4][8];
#pragma unroll
  for (int i = 0; i < 4; i++)
#pragma unroll
    for (int j = 0; j < 8; j++) acc[i][j] = f32x4{0.f, 0.f, 0.f, 0.f};

  gemm_core_wide(A + (size_t)bm * 128 * HC, W + (size_t)bn * 256 * HC, lsA, lsB, acc, tid);

  const int h = bn * 2 + wc;
#pragma unroll
  for (int nj = 0; nj < 4; nj++) {
    const int dlo = nj * 16 + l16;
    const float invf = __expf((float)dlo * (-0.14391156831212787f));
#pragma unroll
    for (int mi = 0; mi < 4; mi++)
#pragma unroll
      for (int rr = 0; rr < 4; rr++) {
        const int m = bm * 128 + wr * 64 + mi * 16 + quad * 4 + rr;
        const int t = m & 255, b = m >> 8;
        float ang = (float)t * invf;
        float sn, cs;
        __sincosf(ang, &sn, &cs);
        float lo = acc[mi][nj][rr], hi = acc[mi][nj + 4][rr];
        size_t base = (((size_t)b * HH + h) * HT + t) * HD;
        outp[base + dlo] = f2bf(lo * cs - hi * sn);
        outp[base + 64 + dlo] = f2bf(hi * cs + lo * sn);
      }
  }
}

// V projection GEMM -> V^T layout [B,H,D,T]: grid (64, 8).
// A-operand = wv channel tile (128 ch = one head), B-operand = x token tile (256).
__global__ __launch_bounds__(256, 2) void gemm_v(const unsigned short* __restrict__ W2,
                                                 const unsigned short* __restrict__ A,
                                                 unsigned short* __restrict__ Vto) {
  __shared__ __align__(16) unsigned short lsA[2 * 128 * 32];
  __shared__ __align__(16) unsigned short lsB[2 * 256 * 32];
  const int tid = threadIdx.x;
  const int lane = tid & 63, wave = tid >> 6;
  const int l16 = lane & 15, quad = lane >> 4;
  const int wr = wave >> 1, wc = wave & 1;

  f32x4 acc[4][8];
#pragma unroll
  for (int i = 0; i < 4; i++)
#pragma unroll
    for (int j = 0; j < 8; j++) acc[i][j] = f32x4{0.f, 0.f, 0.f, 0.f};

  int v = blockIdx.y * 64 + blockIdx.x;  // 512 blocks
  int tok = v & 31, ch2 = v >> 5;        // 32 token-tiles x 16 channel-tiles
  gemm_core_wide(W2 + (size_t)ch2 * 128 * HC, A + (size_t)tok * 256 * HC, lsA, lsB, acc, tid);
  const int b = tok, h = ch2;
#pragma unroll
  for (int mi = 0; mi < 4; mi++)
#pragma unroll
    for (int nj = 0; nj < 8; nj++) {
      const int t = wc * 128 + nj * 16 + l16;
#pragma unroll
      for (int rr = 0; rr < 4; rr++) {
        const int d = wr * 64 + mi * 16 + quad * 4 + rr;
        Vto[(((size_t)b * HH + h) * HD + d) * HT + t] = f2bf(acc[mi][nj][rr]);
      }
    }
}

// ---------------- causal flash attention ----------------
// Block = 4 waves; block handles 64 q-rows of one (b,h); wave owns 16 q-rows.
// Q,K in [B,H,T,D] (pre-RoPEd), Vt in [B,H,D,T]. Y written as [B,T,C] bf16.
// T13 defer-max (m214v23): skip mrow/lrow/o rescale when wave-wide max growth <= 8;
// P bounded by e^8, f32-safe; first tile always rescales (mrow = -1e30).
__global__ __launch_bounds__(256) void attn_kernel(const unsigned short* __restrict__ Q,
                                                   const unsigned short* __restrict__ K,
                                                   const unsigned short* __restrict__ Vt,
                                                   unsigned short* __restrict__ Y) {
  const int g = blockIdx.x;
  const int wq = 3 - (g >> 9);
  const int bh = g & 511;
  const int wave = threadIdx.x >> 6;
  const int lane = threadIdx.x & 63;
  const int quad = lane >> 4, l16 = lane & 15;

  const unsigned short* Qh = Q + (size_t)bh * HT * HD;
  const unsigned short* Kh = K + (size_t)bh * HT * HD;
  const unsigned short* Vh = Vt + (size_t)bh * HD * HT;

  __shared__ __align__(16) unsigned short P[4][16 * 72];
  unsigned short* Pw = P[wave];

  const int qrow = wq * 64 + wave * 16;

  bf16x8 qf[4];
#pragma unroll
  for (int ks = 0; ks < 4; ks++)
    qf[ks] = *(const bf16x8*)(Qh + (size_t)(qrow + l16) * HD + ks * 32 + quad * 8);

  f32x4 o[8];
#pragma unroll
  for (int di = 0; di < 8; di++) o[di] = f32x4{0.f, 0.f, 0.f, 0.f};
  float mrow[4], lrow[4];
#pragma unroll
  for (int r = 0; r < 4; r++) { mrow[r] = -1e30f; lrow[r] = 0.f; }

  const float scale = 0.088388347648318447f;  // 1/sqrt(128)

  for (int ct = 0; ct <= wq; ++ct) {
    f32x4 s[4];
#pragma unroll
    for (int ni = 0; ni < 4; ni++) s[ni] = f32x4{0.f, 0.f, 0.f, 0.f};
    const int nimax = (ct == wq) ? wave : 3;
#pragma unroll
    for (int ks = 0; ks < 4; ks++) {
#pragma unroll
      for (int ni = 0; ni < 4; ni++) {
        if (ni <= nimax) {
          bf16x8 kf = *(const bf16x8*)(Kh + (size_t)(ct * 64 + ni * 16 + l16) * HD + ks * 32 + quad * 8);
          s[ni] = __builtin_amdgcn_mfma_f32_16x16x32_bf16(qf[ks], kf, s[ni], 0, 0, 0);
        }
      }
    }
    if (ct == wq) {
#pragma unroll
      for (int ni = 0; ni < 4; ni++)
#pragma unroll
        for (int r = 0; r < 4; r++) {
          int qr = wave * 16 + quad * 4 + r;
          int kc = ni * 16 + l16;
          s[ni][r] = (kc <= qr) ? s[ni][r] * scale : -1e30f;
        }
    } else {
#pragma unroll
      for (int ni = 0; ni < 4; ni++)
#pragma unroll
        for (int r = 0; r < 4; r++) s[ni][r] *= scale;
    }
    // per-row max (uniform within 16-lane group)
    float pm[4];
#pragma unroll
    for (int r = 0; r < 4; r++) {
      float v = fmaxf(fmaxf(s[0][r], s[1][r]), fmaxf(s[2][r], s[3][r]));
      v = fmaxf(v, __shfl_xor(v, 1, 64));
      v = fmaxf(v, __shfl_xor(v, 2, 64));
      v = fmaxf(v, __shfl_xor(v, 4, 64));
      v = fmaxf(v, __shfl_xor(v, 8, 64));
      pm[r] = v;
    }
    // T13 defer-max: wave-uniform rescale-needed test (max growth across all 16 rows)
    float ex = fmaxf(fmaxf(pm[0] - mrow[0], pm[1] - mrow[1]),
                     fmaxf(pm[2] - mrow[2], pm[3] - mrow[3]));
    ex = fmaxf(ex, __shfl_xor(ex, 16, 64));
    ex = fmaxf(ex, __shfl_xor(ex, 32, 64));
    if (ex > 8.f) {
#pragma unroll
      for (int r = 0; r < 4; r++) {
        float mnew = fmaxf(mrow[r], pm[r]);
        float alpha = __expf(mrow[r] - mnew);
        mrow[r] = mnew;
        lrow[r] *= alpha;
#pragma unroll
        for (int di = 0; di < 8; di++) o[di][r] *= alpha;
      }
    }
#pragma unroll
    for (int r = 0; r < 4; r++) {
      float rs = 0.f;
#pragma unroll
      for (int ni = 0; ni < 4; ni++) {
        float e = __expf(s[ni][r] - mrow[r]);
        s[ni][r] = e;
        rs += e;
      }
      rs += __shfl_xor(rs, 1, 64);
      rs += __shfl_xor(rs, 2, 64);
      rs += __shfl_xor(rs, 4, 64);
      rs += __shfl_xor(rs, 8, 64);
      lrow[r] += rs;
    }
#pragma unroll
    for (int ni = 0; ni < 4; ni++)
#pragma unroll
      for (int r = 0; r < 4; r++)
        Pw[(quad * 4 + r) * 72 + ni * 16 + l16] = f2bf(s[ni][r]);
#pragma unroll
    for (int ks = 0; ks < 2; ks++) {
      bf16x8 pf = *(const bf16x8*)(Pw + (size_t)l16 * 72 + ks * 32 + quad * 8);
#pragma unroll
      for (int di = 0; di < 8; di++) {
        bf16x8 vf = *(const bf16x8*)(Vh + (size_t)(di * 16 + l16) * HT + ct * 64 + ks * 32 + quad * 8);
        o[di] = __builtin_amdgcn_mfma_f32_16x16x32_bf16(pf, vf, o[di], 0, 0, 0);
      }
    }
  }

  const int b = bh >> 4, h = bh & 15;
#pragma unroll
  for (int r = 0; r < 4; r++) {
    float inv = 1.f / lrow[r];
    int t = qrow + quad * 4 + r;
    size_t rowb = ((size_t)b * HT + t) * HC + h * HD;
#pragma unroll
    for (int di = 0; di < 8; di++)
      Y[rowb + di * 16 + l16] = f2bf(o[di][r] * inv);
  }
}

// ---------------- launch ----------------
extern "C" void kernel_launch(void* const* d_in, const int* in_sizes, int n_in,
                              void* d_out, int out_size, void* d_ws, size_t ws_size,
                              hipStream_t stream) {
  const float* x  = (const float*)d_in[0];
  const float* wq = (const float*)d_in[1];
  const float* wk = (const float*)d_in[2];
  const float* wv = (const float*)d_in[3];
  const float* wo = (const float*)d_in[4];
  float* out = (float*)d_out;

  char* ws = (char*)d_ws;
  const size_t MB = (size_t)1 << 20;
  unsigned short* wqb = (unsigned short*)(ws + 0 * MB);
  unsigned short* wkb = (unsigned short*)(ws + 8 * MB);
  unsigned short* wvb = (unsigned short*)(ws + 16 * MB);
  unsigned short* wob = (unsigned short*)(ws + 24 * MB);
  unsigned short* xb  = (unsigned short*)(ws + 32 * MB);
  unsigned short* Qb  = (unsigned short*)(ws + 64 * MB);
  unsigned short* Kb  = (unsigned short*)(ws + 96 * MB);
  unsigned short* Vtb = (unsigned short*)(ws + 128 * MB);
  unsigned short* Yb  = xb;  // reuse x's bf16 buffer after QKV GEMMs

  cvt_all<<<32768, 256, 0, stream>>>(x, wq, wk, wv, wo, xb, wqb, wkb, wvb, wob);

  gemm_qk<<<dim3(64, 8), 256, 0, stream>>>(xb, wqb, Qb);
  gemm_qk<<<dim3(64, 8), 256, 0, stream>>>(xb, wkb, Kb);
  gemm_v<<<dim3(64, 8), 256, 0, stream>>>(wvb, xb, Vtb);

  attn_kernel<<<2048, 256, 0, stream>>>(Qb, Kb, Vtb, Yb);

  gemm_out<<<dim3(64, 8), 256, 0, stream>>>(Yb, wob, out);
}

// Round 6
// 492.336 us; speedup vs baseline: 1.0319x; 1.0319x over previous
//
#include <hip/hip_runtime.h>

#define HB 32
#define HT 256
#define HC 2048
#define HH 16
#define HD 128
#define HM (HB * HT)  // 8192

typedef __bf16 bf16x8 __attribute__((ext_vector_type(8)));
typedef float f32x4 __attribute__((ext_vector_type(4)));

__device__ __forceinline__ unsigned short f2bf(float f) {
  unsigned u = __float_as_uint(f);
  u += 0x7FFFu + ((u >> 16) & 1u);  // round-to-nearest-even
  return (unsigned short)(u >> 16);
}

// ---------------- fused fp32 -> bf16 convert (x + 4 weights) ----------------
__global__ __launch_bounds__(256) void cvt_all(
    const float* __restrict__ x, const float* __restrict__ wq, const float* __restrict__ wk,
    const float* __restrict__ wv, const float* __restrict__ wo,
    unsigned short* __restrict__ xb, unsigned short* __restrict__ wqb,
    unsigned short* __restrict__ wkb, unsigned short* __restrict__ wvb,
    unsigned short* __restrict__ wob) {
  size_t i = (size_t)blockIdx.x * 256 + threadIdx.x;
  const float* src;
  unsigned short* dst;
  size_t off;
  if (i < 4194304) {
    src = x; dst = xb; off = i;
  } else {
    size_t j = i - 4194304;
    int w = (int)(j >> 20);
    off = j & 1048575;
    src = (w == 0) ? wq : (w == 1) ? wk : (w == 2) ? wv : wo;
    dst = (w == 0) ? wqb : (w == 1) ? wkb : (w == 2) ? wvb : wob;
  }
  float4 v = ((const float4*)src)[off];
  ushort4 o;
  o.x = f2bf(v.x); o.y = f2bf(v.y); o.z = f2bf(v.z); o.w = f2bf(v.w);
  ((ushort4*)dst)[off] = o;
}

// ---------------- GEMM core: 128x256 block tile, BK=64, 16x16x32 MFMA ----------------
// Round-3 verified config (SQ_LDS_BANK_CONFLICT = 0, 204 us for 3 GEMMs): 4 waves,
// 48 KiB, stage-all -> barrier -> compute, 2 blocks/CU inter-block overlap. Tiles as
// two [rows][32] k-half planes (64B pitch); fragment reads 16 consecutive rows at
// chunk = quad ^ ((l16>>1)&3) -> 2-way max (free, m136). DO NOT restructure: 8-phase
// at this occupancy regressed twice (rounds 1-2); m131/m99 say source pipelining on
// this structure is neutral.
__device__ __forceinline__ void gl_lds16(const unsigned short* g, unsigned short* l) {
  __builtin_amdgcn_global_load_lds((const __attribute__((address_space(1))) void*)g,
                                   (__attribute__((address_space(3))) void*)l, 16, 0, 0);
}

// Per wave: 64x128 output = acc[4 m-frags][8 n-frags], 16x16x32 MFMA.
// C-layout (m89-verified): row = quad*4 + reg, col = l16.
__device__ __forceinline__ void gemm_core_wide(const unsigned short* __restrict__ Ab,
                                               const unsigned short* __restrict__ Wb,
                                               unsigned short* lsA, unsigned short* lsB,
                                               f32x4 acc[4][8], int tid) {
  const int lane = tid & 63, wave = tid >> 6;
  const int l16 = lane & 15, quad = lane >> 4;
  const int wr = wave >> 1, wc = wave & 1;
  // swizzle is row-independent at 16-aligned fragment rows: bits 1-2 of row == bits 1-2 of l16
  const int ch = (quad ^ ((l16 >> 1) & 3)) * 8;

  for (int kt = 0; kt < HC / 64; ++kt) {
    __syncthreads();
    // stage A: [2 kh][128 rows][32] = 1024 x 16B chunks; vrow = kh*128 + row
#pragma unroll
    for (int i = 0; i < 4; i++) {
      int c = i * 256 + tid;
      int vrow = c >> 2, slot = c & 3;
      int gc = slot ^ ((vrow >> 1) & 3);
      int row = vrow & 127, kh = vrow >> 7;
      gl_lds16(Ab + (size_t)row * HC + kt * 64 + kh * 32 + gc * 8, lsA + c * 8);
    }
    // stage B: [2 kh][256 rows][32] = 2048 chunks
#pragma unroll
    for (int i = 0; i < 8; i++) {
      int c = i * 256 + tid;
      int vrow = c >> 2, slot = c & 3;
      int gc = slot ^ ((vrow >> 1) & 3);
      int row = vrow & 255, kh = vrow >> 8;
      gl_lds16(Wb + (size_t)row * HC + kt * 64 + kh * 32 + gc * 8, lsB + c * 8);
    }
    __syncthreads();
#pragma unroll
    for (int kh = 0; kh < 2; ++kh) {
      bf16x8 af[4], bfr[8];
#pragma unroll
      for (int mi = 0; mi < 4; mi++) {
        int r = wr * 64 + mi * 16 + l16;
        af[mi] = *(const bf16x8*)(lsA + (kh * 128 + r) * 32 + ch);
      }
#pragma unroll
      for (int nj = 0; nj < 8; nj++) {
        int r = wc * 128 + nj * 16 + l16;
        bfr[nj] = *(const bf16x8*)(lsB + (kh * 256 + r) * 32 + ch);
      }
#pragma unroll
      for (int mi = 0; mi < 4; mi++)
#pragma unroll
        for (int nj = 0; nj < 8; nj++)
          acc[mi][nj] = __builtin_amdgcn_mfma_f32_16x16x32_bf16(af[mi], bfr[nj], acc[mi][nj], 0, 0, 0);
    }
  }
}

// Output projection GEMM: fp32 out [M, 2048]; grid (64, 8)
__global__ __launch_bounds__(256, 2) void gemm_out(const unsigned short* __restrict__ A,
                                                   const unsigned short* __restrict__ W,
                                                   float* __restrict__ outp) {
  __shared__ __align__(16) unsigned short lsA[2 * 128 * 32];
  __shared__ __align__(16) unsigned short lsB[2 * 256 * 32];
  const int tid = threadIdx.x;
  const int lane = tid & 63, wave = tid >> 6;
  const int l16 = lane & 15, quad = lane >> 4;
  const int wr = wave >> 1, wc = wave & 1;
  const int bm = blockIdx.x, bn = blockIdx.y;

  f32x4 acc[4][8];
#pragma unroll
  for (int i = 0; i < 4; i++)
#pragma unroll
    for (int j = 0; j < 8; j++) acc[i][j] = f32x4{0.f, 0.f, 0.f, 0.f};

  gemm_core_wide(A + (size_t)bm * 128 * HC, W + (size_t)bn * 256 * HC, lsA, lsB, acc, tid);

#pragma unroll
  for (int mi = 0; mi < 4; mi++)
#pragma unroll
    for (int nj = 0; nj < 8; nj++) {
      const int n = bn * 256 + wc * 128 + nj * 16 + l16;
#pragma unroll
      for (int rr = 0; rr < 4; rr++) {
        const int m = bm * 128 + wr * 64 + mi * 16 + quad * 4 + rr;
        outp[(size_t)m * HC + n] = acc[mi][nj][rr];
      }
    }
}

// Fused QKV GEMM: grid (64, 24); blockIdx.y>>3 selects {Q,K,V}.
// Q,K -> [B,H,T,D] with RoPE fused; V -> [B,H,D,T] via operand swap (coalesced).
__global__ __launch_bounds__(256, 2) void gemm_qkv(const unsigned short* __restrict__ A,
                                                    const unsigned short* __restrict__ W0,
                                                    const unsigned short* __restrict__ W1,
                                                    const unsigned short* __restrict__ W2,
                                                    unsigned short* __restrict__ Qo,
                                                    unsigned short* __restrict__ Ko,
                                                    unsigned short* __restrict__ Vto) {
  __shared__ __align__(16) unsigned short lsA[2 * 128 * 32];
  __shared__ __align__(16) unsigned short lsB[2 * 256 * 32];
  const int tid = threadIdx.x;
  const int lane = tid & 63, wave = tid >> 6;
  const int l16 = lane & 15, quad = lane >> 4;
  const int wr = wave >> 1, wc = wave & 1;
  const int bm = blockIdx.x;
  const int which = blockIdx.y >> 3;
  const int bn = blockIdx.y & 7;

  f32x4 acc[4][8];
#pragma unroll
  for (int i = 0; i < 4; i++)
#pragma unroll
    for (int j = 0; j < 8; j++) acc[i][j] = f32x4{0.f, 0.f, 0.f, 0.f};

  if (which < 2) {
    const unsigned short* W = (which == 0) ? W0 : W1;
    unsigned short* outp = (which == 0) ? Qo : Ko;
    gemm_core_wide(A + (size_t)bm * 128 * HC, W + (size_t)bn * 256 * HC, lsA, lsB, acc, tid);
    // Wave's 128 cols = one head: h = bn*2 + wc. RoPE pair: acc[mi][nj] (d) with
    // acc[mi][nj+4] (d+64), d = nj*16 + l16, nj in {0..3}.
    const int h = bn * 2 + wc;
#pragma unroll
    for (int nj = 0; nj < 4; nj++) {
      const int dlo = nj * 16 + l16;
      const float invf = __expf((float)dlo * (-0.14391156831212787f));
#pragma unroll
      for (int mi = 0; mi < 4; mi++)
#pragma unroll
        for (int rr = 0; rr < 4; rr++) {
          const int m = bm * 128 + wr * 64 + mi * 16 + quad * 4 + rr;
          const int t = m & 255, b = m >> 8;
          float ang = (float)t * invf;
          float sn, cs;
          __sincosf(ang, &sn, &cs);
          float lo = acc[mi][nj][rr], hi = acc[mi][nj + 4][rr];
          size_t base = (((size_t)b * HH + h) * HT + t) * HD;
          outp[base + dlo] = f2bf(lo * cs - hi * sn);
          outp[base + 64 + dlo] = f2bf(hi * cs + lo * sn);
        }
    }
  } else {
    // V^T: A-operand = wv channel tile (128 ch = one head), B-operand = x token tile (256).
    int v = bn * 64 + bm;            // 512 blocks
    int tok = v & 31, ch2 = v >> 5;  // 32 token-tiles x 16 channel-tiles
    gemm_core_wide(W2 + (size_t)ch2 * 128 * HC, A + (size_t)tok * 256 * HC, lsA, lsB, acc, tid);
    const int b = tok, h = ch2;
#pragma unroll
    for (int mi = 0; mi < 4; mi++)
#pragma unroll
      for (int nj = 0; nj < 8; nj++) {
        const int t = wc * 128 + nj * 16 + l16;
#pragma unroll
        for (int rr = 0; rr < 4; rr++) {
          const int d = wr * 64 + mi * 16 + quad * 4 + rr;
          Vto[(((size_t)b * HH + h) * HD + d) * HT + t] = f2bf(acc[mi][nj][rr]);
        }
      }
  }
}

// ---------------- causal flash attention ----------------
// Round-4 diagnosis: 84.5 us, MfmaUtil 4.4%, VALU 19%, HBM 17%, Occupancy 27.6%
// -> latency-bound with occupancy decay from causal work imbalance (1:4 per block).
// Fixes: (1) pair q-tiles {3,0} / {2,1} per block -> 1024 blocks x uniform 5
// tile-iters; at 84-116 VGPR (16 waves/CU tier) exactly 4 blocks/CU = ALL blocks
// resident, no tail. (2) T14-style hoist of the ks=0 half of V loads (32 VGPR)
// to before softmax: V is independent of softmax, so its L2 latency (~200cy)
// hides under the exp/shfl chain. VGPR must stay <= 128 (cliff to 2 blocks/CU).
// T13 defer-max retained.
__global__ __launch_bounds__(256) void attn_kernel(const unsigned short* __restrict__ Q,
                                                   const unsigned short* __restrict__ K,
                                                   const unsigned short* __restrict__ Vt,
                                                   unsigned short* __restrict__ Y) {
  const int g = blockIdx.x;      // 1024 blocks
  const int bh = g & 511;
  const int pairp = g >> 9;      // 0 -> {3,0}, 1 -> {2,1}
  const int wave = threadIdx.x >> 6;
  const int lane = threadIdx.x & 63;
  const int quad = lane >> 4, l16 = lane & 15;

  const unsigned short* Qh = Q + (size_t)bh * HT * HD;
  const unsigned short* Kh = K + (size_t)bh * HT * HD;
  const unsigned short* Vh = Vt + (size_t)bh * HD * HT;

  __shared__ __align__(16) unsigned short P[4][16 * 72];
  unsigned short* Pw = P[wave];

  const float scale = 0.088388347648318447f;  // 1/sqrt(128)
  const int b = bh >> 4, h = bh & 15;

  for (int half = 0; half < 2; ++half) {
    const int wq = (pairp == 0) ? (half == 0 ? 3 : 0) : (half == 0 ? 2 : 1);
    const int qrow = wq * 64 + wave * 16;

    bf16x8 qf[4];
#pragma unroll
    for (int ks = 0; ks < 4; ks++)
      qf[ks] = *(const bf16x8*)(Qh + (size_t)(qrow + l16) * HD + ks * 32 + quad * 8);

    f32x4 o[8];
#pragma unroll
    for (int di = 0; di < 8; di++) o[di] = f32x4{0.f, 0.f, 0.f, 0.f};
    float mrow[4], lrow[4];
#pragma unroll
    for (int r = 0; r < 4; r++) { mrow[r] = -1e30f; lrow[r] = 0.f; }

    for (int ct = 0; ct <= wq; ++ct) {
      f32x4 s[4];
#pragma unroll
      for (int ni = 0; ni < 4; ni++) s[ni] = f32x4{0.f, 0.f, 0.f, 0.f};
      const int nimax = (ct == wq) ? wave : 3;
#pragma unroll
      for (int ks = 0; ks < 4; ks++) {
#pragma unroll
        for (int ni = 0; ni < 4; ni++) {
          if (ni <= nimax) {
            bf16x8 kf = *(const bf16x8*)(Kh + (size_t)(ct * 64 + ni * 16 + l16) * HD + ks * 32 + quad * 8);
            s[ni] = __builtin_amdgcn_mfma_f32_16x16x32_bf16(qf[ks], kf, s[ni], 0, 0, 0);
          }
        }
      }
      // T14 hoist: issue ks=0 half of the V tile now; latency hides under softmax.
      bf16x8 vf0[8];
#pragma unroll
      for (int di = 0; di < 8; di++)
        vf0[di] = *(const bf16x8*)(Vh + (size_t)(di * 16 + l16) * HT + ct * 64 + quad * 8);

      if (ct == wq) {
#pragma unroll
        for (int ni = 0; ni < 4; ni++)
#pragma unroll
          for (int r = 0; r < 4; r++) {
            int qr = wave * 16 + quad * 4 + r;
            int kc = ni * 16 + l16;
            s[ni][r] = (kc <= qr) ? s[ni][r] * scale : -1e30f;
          }
      } else {
#pragma unroll
        for (int ni = 0; ni < 4; ni++)
#pragma unroll
          for (int r = 0; r < 4; r++) s[ni][r] *= scale;
      }
      // per-row max (uniform within 16-lane group)
      float pm[4];
#pragma unroll
      for (int r = 0; r < 4; r++) {
        float v = fmaxf(fmaxf(s[0][r], s[1][r]), fmaxf(s[2][r], s[3][r]));
        v = fmaxf(v, __shfl_xor(v, 1, 64));
        v = fmaxf(v, __shfl_xor(v, 2, 64));
        v = fmaxf(v, __shfl_xor(v, 4, 64));
        v = fmaxf(v, __shfl_xor(v, 8, 64));
        pm[r] = v;
      }
      // T13 defer-max: wave-uniform rescale test (max growth across all 16 rows)
      float ex = fmaxf(fmaxf(pm[0] - mrow[0], pm[1] - mrow[1]),
                       fmaxf(pm[2] - mrow[2], pm[3] - mrow[3]));
      ex = fmaxf(ex, __shfl_xor(ex, 16, 64));
      ex = fmaxf(ex, __shfl_xor(ex, 32, 64));
      if (ex > 8.f) {
#pragma unroll
        for (int r = 0; r < 4; r++) {
          float mnew = fmaxf(mrow[r], pm[r]);
          float alpha = __expf(mrow[r] - mnew);
          mrow[r] = mnew;
          lrow[r] *= alpha;
#pragma unroll
          for (int di = 0; di < 8; di++) o[di][r] *= alpha;
        }
      }
#pragma unroll
      for (int r = 0; r < 4; r++) {
        float rs = 0.f;
#pragma unroll
        for (int ni = 0; ni < 4; ni++) {
          float e = __expf(s[ni][r] - mrow[r]);
          s[ni][r] = e;
          rs += e;
        }
        rs += __shfl_xor(rs, 1, 64);
        rs += __shfl_xor(rs, 2, 64);
        rs += __shfl_xor(rs, 4, 64);
        rs += __shfl_xor(rs, 8, 64);
        lrow[r] += rs;
      }
#pragma unroll
      for (int ni = 0; ni < 4; ni++)
#pragma unroll
        for (int r = 0; r < 4; r++)
          Pw[(quad * 4 + r) * 72 + ni * 16 + l16] = f2bf(s[ni][r]);
      // PV: ks=0 uses the hoisted vf0; ks=1 loads inline.
      {
        bf16x8 pf = *(const bf16x8*)(Pw + (size_t)l16 * 72 + quad * 8);
#pragma unroll
        for (int di = 0; di < 8; di++)
          o[di] = __builtin_amdgcn_mfma_f32_16x16x32_bf16(pf, vf0[di], o[di], 0, 0, 0);
      }
      {
        bf16x8 pf = *(const bf16x8*)(Pw + (size_t)l16 * 72 + 32 + quad * 8);
#pragma unroll
        for (int di = 0; di < 8; di++) {
          bf16x8 vf = *(const bf16x8*)(Vh + (size_t)(di * 16 + l16) * HT + ct * 64 + 32 + quad * 8);
          o[di] = __builtin_amdgcn_mfma_f32_16x16x32_bf16(pf, vf, o[di], 0, 0, 0);
        }
      }
    }

#pragma unroll
    for (int r = 0; r < 4; r++) {
      float inv = 1.f / lrow[r];
      int t = qrow + quad * 4 + r;
      size_t rowb = ((size_t)b * HT + t) * HC + h * HD;
#pragma unroll
      for (int di = 0; di < 8; di++)
        Y[rowb + di * 16 + l16] = f2bf(o[di][r] * inv);
    }
  }
}

// ---------------- launch ----------------
extern "C" void kernel_launch(void* const* d_in, const int* in_sizes, int n_in,
                              void* d_out, int out_size, void* d_ws, size_t ws_size,
                              hipStream_t stream) {
  const float* x  = (const float*)d_in[0];
  const float* wq = (const float*)d_in[1];
  const float* wk = (const float*)d_in[2];
  const float* wv = (const float*)d_in[3];
  const float* wo = (const float*)d_in[4];
  float* out = (float*)d_out;

  char* ws = (char*)d_ws;
  const size_t MB = (size_t)1 << 20;
  unsigned short* wqb = (unsigned short*)(ws + 0 * MB);
  unsigned short* wkb = (unsigned short*)(ws + 8 * MB);
  unsigned short* wvb = (unsigned short*)(ws + 16 * MB);
  unsigned short* wob = (unsigned short*)(ws + 24 * MB);
  unsigned short* xb  = (unsigned short*)(ws + 32 * MB);
  unsigned short* Qb  = (unsigned short*)(ws + 64 * MB);
  unsigned short* Kb  = (unsigned short*)(ws + 96 * MB);
  unsigned short* Vtb = (unsigned short*)(ws + 128 * MB);
  unsigned short* Yb  = xb;  // reuse x's bf16 buffer after QKV GEMMs

  cvt_all<<<32768, 256, 0, stream>>>(x, wq, wk, wv, wo, xb, wqb, wkb, wvb, wob);

  gemm_qkv<<<dim3(HM / 128, 24), 256, 0, stream>>>(xb, wqb, wkb, wvb, Qb, Kb, Vtb);

  attn_kernel<<<1024, 256, 0, stream>>>(Qb, Kb, Vtb, Yb);

  gemm_out<<<dim3(HM / 128, HC / 256), 256, 0, stream>>>(Yb, wob, out);
}